// Round 3
// baseline (1673.067 us; speedup 1.0000x reference)
//
#include <hip/hip_runtime.h>
#include <math.h>

// Problem constants (B=4, S=4096, H=4096, E=64, top_k=8)
#define H_DIM  4096
#define E_NUM  64
#define N_TOK  16384           // B*S
#define TOPK   8
#define KSEG   1024            // per-wave K segment (4 waves cover H=4096)
#define NCH    16              // 64-k fp32 chunks per segment

// flat output layout: [probs (N_TOK*64)][indices (N_TOK*8)][gate (N_TOK*64)]
#define N_PROBS  (N_TOK * E_NUM)
#define OFF_IDX  N_PROBS
#define OFF_GATE (N_PROBS + N_TOK * TOPK)

// Single kernel, no workspace (R2's d_ws-size gamble removed), no inline asm
// (R2's hand-rolled s_load removed). lane = token; each of the block's 4
// waves handles a 1024-k segment of the same 64 tokens; partials reduced
// deterministically through LDS. W addresses are wave-uniform (kbase via
// readfirstlane) and all stores happen after the k-loop, so the compiler's
// uniform-load pass can select s_load — W broadcasts from SGPRs for free.
__global__ __launch_bounds__(256, 1)
void gating_kernel(const float* __restrict__ x, const float* __restrict__ W,
                   float* __restrict__ out) {
  __shared__ float ps[4][E_NUM][64];   // [kseg][expert][token] = 64 KB exactly

  const int tid   = threadIdx.x;
  const int lane  = tid & 63;
  const int wv    = __builtin_amdgcn_readfirstlane(tid >> 6);  // uniform wave id
  const int tok0  = blockIdx.x * 64;
  const int kbase = wv * KSEG;

  const float* __restrict__ xrow = x + (size_t)(tok0 + lane) * H_DIM + kbase;
  const float* __restrict__ wseg = W + kbase;   // uniform base

  double acc64[E_NUM];
#pragma unroll
  for (int e = 0; e < E_NUM; ++e) acc64[e] = 0.0;

  // x software-prefetch: one full iteration (~2048 VALU cyc) ahead of use.
  float4 cur[4];
#pragma unroll
  for (int q = 0; q < 4; ++q) cur[q] = *(const float4*)(xrow + 4 * q);

#pragma unroll 1
  for (int c = 0; c < NCH; ++c) {
    float ca[E_NUM];                   // fp32 within a 64-k chunk
#pragma unroll
    for (int e = 0; e < E_NUM; ++e) ca[e] = 0.f;

#pragma unroll 1
    for (int s = 0; s < 4; ++s) {      // 4 x 16-k sub-iterations
      const int i = 4 * c + s;

      float4 use[4];
#pragma unroll
      for (int q = 0; q < 4; ++q) use[q] = cur[q];

      int ni = i + 1; if (ni > 63) ni = 63;   // clamp: last iter reloads (harmless)
#pragma unroll
      for (int q = 0; q < 4; ++q)
        cur[q] = *(const float4*)(xrow + 16 * ni + 4 * q);

      const float xk[16] = {use[0].x, use[0].y, use[0].z, use[0].w,
                            use[1].x, use[1].y, use[1].z, use[1].w,
                            use[2].x, use[2].y, use[2].z, use[2].w,
                            use[3].x, use[3].y, use[3].z, use[3].w};

      // 64 independent FMA chains (one per expert) — scheduler interleaves,
      // dep distance >> 4-cyc FMA latency.
#pragma unroll
      for (int e0 = 0; e0 < E_NUM; e0 += 4) {
#pragma unroll
        for (int j = 0; j < 4; ++j) {
          const float* wp = wseg + (size_t)(e0 + j) * H_DIM + 16 * i; // uniform
#pragma unroll
          for (int q = 0; q < 4; ++q) {
            const float4 wq = *(const float4*)(wp + 4 * q);
            ca[e0 + j] = fmaf(xk[4 * q + 0], wq.x, ca[e0 + j]);
            ca[e0 + j] = fmaf(xk[4 * q + 1], wq.y, ca[e0 + j]);
            ca[e0 + j] = fmaf(xk[4 * q + 2], wq.z, ca[e0 + j]);
            ca[e0 + j] = fmaf(xk[4 * q + 3], wq.w, ca[e0 + j]);
          }
        }
      }
    }

#pragma unroll
    for (int e = 0; e < E_NUM; ++e) acc64[e] += (double)ca[e];  // fp64 across chunks
  }

  // ---- per-wave partials to LDS ([s][e][t]: lanes vary t -> stride-1, free)
#pragma unroll
  for (int e = 0; e < E_NUM; ++e) ps[wv][e][lane] = (float)acc64[e];
  __syncthreads();

  // ---- fixed-order fp64 reduce over the 4 segments; result into ps[0].
  // Each (e,t) cell is read and written by exactly one thread: no hazard.
#pragma unroll
  for (int p = 0; p < 16; ++p) {
    const int f = tid + 256 * p;
    const int t = f & 63;
    const int e = f >> 6;
    double v = 0.0;
#pragma unroll
    for (int s = 0; s < 4; ++s) v += (double)ps[s][e][t];
    ps[0][e][t] = (float)v;
  }
  __syncthreads();

  // ---- gate_logit: coalesced global writes (flat idx tok0*64 + g)
  float* __restrict__ gate = out + OFF_GATE;
#pragma unroll
  for (int p = 0; p < 16; ++p) {
    const int g = tid + 256 * p;                 // t = g>>6, e = g&63
    gate[(size_t)tok0 * E_NUM + g] = ps[0][g & 63][g >> 6];
  }
  __syncthreads();   // gate reads complete before top-8 mutates ps[0]

  // ---- per-token top-8 (strict > == jax lowest-index tie-break) + softmax
  if (tid < 64) {
    const int t = tid;
    float vals[TOPK];
    int   idxs[TOPK];
#pragma unroll
    for (int r = 0; r < TOPK; ++r) {
      float best = -INFINITY;
      int   bi   = 0;
      for (int e = 0; e < E_NUM; ++e) {
        const float v = ps[0][e][t];             // lanes vary t: conflict-free
        if (v > best) { best = v; bi = e; }
      }
      vals[r] = best;
      idxs[r] = bi;
      ps[0][bi][t] = -INFINITY;
    }
    const float m = vals[0];
    float ssum = 0.f, pr[TOPK];
#pragma unroll
    for (int r = 0; r < TOPK; ++r) { pr[r] = __expf(vals[r] - m); ssum += pr[r]; }
    const float inv = 1.0f / ssum;
    for (int e = 0; e < E_NUM; ++e) ps[0][e][t] = 0.f;
#pragma unroll
    for (int r = 0; r < TOPK; ++r) ps[0][idxs[r]][t] = pr[r] * inv;

    // indices land in a flat fp32 buffer -> write as float (exact for 0..63)
    float* __restrict__ oidx = out + OFF_IDX + (size_t)(tok0 + t) * TOPK;
#pragma unroll
    for (int r = 0; r < TOPK; ++r) oidx[r] = (float)idxs[r];
  }
  __syncthreads();

  // ---- coalesced sparse_probs writeback
  float* __restrict__ oprob = out + (size_t)tok0 * E_NUM;
#pragma unroll
  for (int p = 0; p < 16; ++p) {
    const int g = tid + 256 * p;
    oprob[g] = ps[0][g & 63][g >> 6];
  }
}

extern "C" void kernel_launch(void* const* d_in, const int* in_sizes, int n_in,
                              void* d_out, int out_size, void* d_ws, size_t ws_size,
                              hipStream_t stream) {
  const float* x = (const float*)d_in[0];
  const float* W = (const float*)d_in[1];
  float* out = (float*)d_out;
  gating_kernel<<<dim3(N_TOK / 64), dim3(256), 0, stream>>>(x, W, out);
}

// Round 4
// 1346.795 us; speedup vs baseline: 1.2423x; 1.2423x over previous
//
#include <hip/hip_runtime.h>
#include <math.h>

// Problem constants (B=4, S=4096, H=4096, E=64, top_k=8)
#define H_DIM  4096
#define E_NUM  64
#define N_TOK  16384           // B*S
#define TOPK   8
#define ET     16              // experts per lane
#define CK     64              // fp32 chunk (16 substeps of 4 k)

// flat output layout: [probs (N_TOK*64)][indices (N_TOK*8)][gate (N_TOK*64)]
#define N_PROBS  (N_TOK * E_NUM)
#define OFF_IDX  N_PROBS
#define OFF_GATE (N_PROBS + N_TOK * TOPK)

// Design (R4): lane = token (coalesced 1024 B x-loads, ring of 8 float4 in
// flight = ~1024 cyc of HBM-latency cover), 16 experts per lane (16 fp32 +
// 16 fp64 accumulators = 48 VGPRs — R3 died at 192), W via lane-uniform
// vector loads (1 L1 transaction each), double-buffered with even/odd unroll.
// ZERO LDS and ZERO __syncthreads in the main loop; a raw s_barrier (no
// waitcnt drain) per 64-k chunk keeps the 4 waves' x streams L1/L2-aligned.
__global__ __launch_bounds__(256, 1)
void gating_kernel(const float* __restrict__ x, const float* __restrict__ W,
                   float* __restrict__ out) {
  __shared__ float lg[64][E_NUM + 1];   // epilogue only (16.6 KB)

  const int tid  = threadIdx.x;
  const int lane = tid & 63;
  const int wv   = __builtin_amdgcn_readfirstlane(tid >> 6);  // wave id 0..3
  const int tok0 = blockIdx.x * 64;
  const int tok  = tok0 + lane;
  const int e0   = wv * ET;             // this wave's expert range

  const float* __restrict__ xr = x + (size_t)tok * H_DIM;
  const float* wb[ET];                  // uniform -> SGPR pairs
#pragma unroll
  for (int j = 0; j < ET; ++j) wb[j] = W + (size_t)(e0 + j) * H_DIM;

  // x ring: substeps 0..7 (k = 0..31) in flight
  float4 ring[8];
#pragma unroll
  for (int i = 0; i < 8; ++i) ring[i] = *(const float4*)(xr + 4 * i);

  // W double buffer; wA holds substep 0
  float4 wA[ET], wB[ET];
#pragma unroll
  for (int j = 0; j < ET; ++j) wA[j] = *(const float4*)(wb[j]);

  double accd[ET];
#pragma unroll
  for (int j = 0; j < ET; ++j) accd[j] = 0.0;

#pragma unroll 1
  for (int c = 0; c < H_DIM / CK; ++c) {
    float ca[ET];
#pragma unroll
    for (int j = 0; j < ET; ++j) ca[j] = 0.f;

#pragma unroll
    for (int s = 0; s < 16; ++s) {      // 16 x 4-k substeps = one 64-k chunk
      const int g  = c * 16 + s;        // global substep, k = 4g
      int kn = 4 * (g + 8); if (kn >= H_DIM) kn = 0;   // ring reissue target
      int kw = 4 * (g + 1); if (kw >= H_DIM) kw = 0;   // W prefetch target

      const float4 xv = ring[s & 7];               // consume (vmcnt wait here)
      ring[s & 7] = *(const float4*)(xr + kn);     // reissue: 8 substeps ahead

      // prefetch next substep's W into the other buffer (no register swaps:
      // even substeps compute on wA, odd on wB)
      if ((s & 1) == 0) {
#pragma unroll
        for (int j = 0; j < ET; ++j) wB[j] = *(const float4*)(wb[j] + kw);
#pragma unroll
        for (int j = 0; j < ET; ++j) {
          ca[j] = fmaf(xv.x, wA[j].x, ca[j]);
          ca[j] = fmaf(xv.y, wA[j].y, ca[j]);
          ca[j] = fmaf(xv.z, wA[j].z, ca[j]);
          ca[j] = fmaf(xv.w, wA[j].w, ca[j]);
        }
      } else {
#pragma unroll
        for (int j = 0; j < ET; ++j) wA[j] = *(const float4*)(wb[j] + kw);
#pragma unroll
        for (int j = 0; j < ET; ++j) {
          ca[j] = fmaf(xv.x, wB[j].x, ca[j]);
          ca[j] = fmaf(xv.y, wB[j].y, ca[j]);
          ca[j] = fmaf(xv.z, wB[j].z, ca[j]);
          ca[j] = fmaf(xv.w, wB[j].w, ca[j]);
        }
      }
    }

#pragma unroll
    for (int j = 0; j < ET; ++j) accd[j] += (double)ca[j];  // fp64 across chunks

    // soft wave-alignment: raw barrier WITHOUT the __syncthreads waitcnt
    // drain (a vmcnt(0) here would flush the x ring every chunk). Purely a
    // locality hint — correctness never depends on it.
    __builtin_amdgcn_s_barrier();
  }

  // ---- logits to LDS: lane writes its 16 experts (stride-65 rows: 2-way
  // bank aliasing = free)
#pragma unroll
  for (int j = 0; j < ET; ++j) lg[lane][e0 + j] = (float)accd[j];
  __syncthreads();

  // ---- gate_logit: coalesced global writes
  float* __restrict__ gate = out + OFF_GATE;
#pragma unroll
  for (int p = 0; p < 16; ++p) {
    const int g = tid + 256 * p;                   // t = g>>6, e = g&63
    gate[(size_t)tok0 * E_NUM + g] = lg[g >> 6][g & 63];
  }
  __syncthreads();   // gate reads done before top-8 mutates lg

  // ---- per-token top-8 (strict > == jax lowest-index tie-break) + softmax
  // (R1's twice-passed epilogue, verbatim)
  if (tid < 64) {
    const int t = tid;
    float vals[TOPK];
    int   idxs[TOPK];
#pragma unroll
    for (int r = 0; r < TOPK; ++r) {
      float best = -INFINITY;
      int   bi   = 0;
      for (int e = 0; e < E_NUM; ++e) {
        const float v = lg[t][e];
        if (v > best) { best = v; bi = e; }
      }
      vals[r] = best;
      idxs[r] = bi;
      lg[t][bi] = -INFINITY;
    }
    const float m = vals[0];
    float ssum = 0.f, pr[TOPK];
#pragma unroll
    for (int r = 0; r < TOPK; ++r) { pr[r] = __expf(vals[r] - m); ssum += pr[r]; }
    const float inv = 1.0f / ssum;
    for (int e = 0; e < E_NUM; ++e) lg[t][e] = 0.f;
#pragma unroll
    for (int r = 0; r < TOPK; ++r) lg[t][idxs[r]] = pr[r] * inv;

    // indices land in a flat fp32 buffer -> write as float (exact for 0..63)
    float* __restrict__ oidx = out + OFF_IDX + (size_t)(tok0 + t) * TOPK;
#pragma unroll
    for (int r = 0; r < TOPK; ++r) oidx[r] = (float)idxs[r];
  }
  __syncthreads();

  // ---- coalesced sparse_probs writeback
  float* __restrict__ oprob = out + (size_t)tok0 * E_NUM;
#pragma unroll
  for (int p = 0; p < 16; ++p) {
    const int g = tid + 256 * p;
    oprob[g] = lg[g >> 6][g & 63];
  }
}

extern "C" void kernel_launch(void* const* d_in, const int* in_sizes, int n_in,
                              void* d_out, int out_size, void* d_ws, size_t ws_size,
                              hipStream_t stream) {
  const float* x = (const float*)d_in[0];
  const float* W = (const float*)d_in[1];
  float* out = (float*)d_out;
  gating_kernel<<<dim3(N_TOK / 64), dim3(256), 0, stream>>>(x, W, out);
}